// Round 1
// 107.415 us; speedup vs baseline: 1.0079x; 1.0079x over previous
//
#include <hip/hip_runtime.h>

// SSIM loss, wave-autonomous + register ring buffer. B=32, H=W=512, win=11.
// Each wave: 128-col strip (118 outputs, 2 cols/lane) x 22-row band.
// R11: issue-slot reduction on the R10 structure (tiling/ring/prefetch kept):
//  (a) packed fp32 (v_pk_add/mul/fma via <2 x float> ext_vector) for the
//      column-paired math: vertical moment update/downdate, SSIM epilogue,
//      accumulator. 2x FP32 issue rate on CDNA4.
//  (b) the 5-deep wave_shl:1 u-chain (x4 moments = 20 serialized DPP movs)
//      replaced by one ds_bpermute per moment (lane l+5 fetch) on the idle
//      LDS pipe. ~120 -> ~87 VALU slots per 2-output iteration.
// Vertical moments in registers; trailing 11 rows ring-buffered in VGPRs.
// Horizontal 11-tap A-chain still DPP wave_shl:1. atomicAdd into d_out.

#define WW 512
#define OH 502
#define BANDR 22
#define NBANDS 23
#define INV_N (1.0f / 8064128.0f)   // 32*502*502

typedef float f2 __attribute__((ext_vector_type(2)));

__device__ __forceinline__ f2 splat(float v) {
    f2 r; r.x = v; r.y = v; return r;
}

__device__ __forceinline__ f2 ld2(const float* p) {
    return *(const f2*)p;
}

// lane l receives lane l+1's value; bound_ctrl=1 (OOB -> 0).
__device__ __forceinline__ float shl1(float x) {
    return __int_as_float(__builtin_amdgcn_update_dpp(
        0, __float_as_int(x), 0x130, 0xf, 0xf, true));
}

// 11-tap horizontal window sums for this lane's two columns (2l, 2l+1).
// m = (colsum 2l, colsum 2l+1). A = cols 2l..2l+11 (12 taps) via DPP chain.
// u = col 2l+11 fetched in ONE op from lane l+5 via ds_bpermute (bpa
// precomputed = 4*(lane+5); wrap for lanes >=59 only feeds masked outputs).
// W0 = A - u = cols 2l..2l+10; W1 = A - m.x = cols 2l+1..2l+11.
__device__ __forceinline__ f2 hwin(f2 m, int bpa) {
    float e = m.x + m.y;
    float t = shl1(e);  float A = e + t;
    t = shl1(t);  A += t;
    t = shl1(t);  A += t;
    t = shl1(t);  A += t;
    t = shl1(t);  A += t;
    float u = __int_as_float(
        __builtin_amdgcn_ds_bpermute(bpa, __float_as_int(m.y)));
    f2 r; r.x = A - u; r.y = A - m.x;
    return r;
}

// Packed SSIM for both columns at once. Same fma nesting + rcpf as R10
// (bit-identical per-component numerics).
__device__ __forceinline__ f2 ssim2(f2 s0, f2 s1, f2 sq, f2 sx) {
    const float NP  = 121.f;
    const float cn  = 121.f / 120.f;
    const float C1n = 1e-4f * 121.f * 121.f;
    const float C2n = 9e-4f * 121.f * 121.f;
    f2 m1 = s0 * s1;
    f2 q1 = __builtin_elementwise_fma(s0, s0, s1 * s1);
    f2 A1 = __builtin_elementwise_fma(splat(2.f), m1, splat(C1n));
    f2 B1 = q1 + splat(C1n);
    f2 A2 = __builtin_elementwise_fma(splat(2.f * cn),
              __builtin_elementwise_fma(splat(NP), sx, -m1), splat(C2n));
    f2 B2 = __builtin_elementwise_fma(splat(cn),
              __builtin_elementwise_fma(splat(NP), sq, -q1), splat(C2n));
    f2 num = A1 * A2;
    f2 den = B1 * B2;
    f2 r;
    r.x = __builtin_amdgcn_rcpf(den.x);
    r.y = __builtin_amdgcn_rcpf(den.y);
    return num * r;
}

__global__ __launch_bounds__(256)
void ssim_main(const float* __restrict__ Pg, const float* __restrict__ Tg,
               float* __restrict__ outp) {
    const int tid  = threadIdx.x;
    const int lane = tid & 63;
    const int wv   = tid >> 6;
    const int Wid  = blockIdx.x * 4 + wv;      // 0..3679
    const int img   = Wid / 115;               // 5 strips * 23 bands
    const int rem   = Wid - img * 115;
    const int strip = rem / NBANDS;
    const int band  = rem - strip * NBANDS;

    const int col0 = (strip == 4) ? 472 : strip * 118;
    const int outw = (strip == 4) ? 30 : 118;
    const int y0   = band * BANDR;             // band 22: 484 (18 real rows)

    const int cload = min(col0 + 2 * lane, 510);
    const bool ok   = lane < (outw >> 1);
    const int bpa   = (lane + 5) << 2;         // ds_bpermute byte addr

    const float* Pb = Pg + img * (WW * WW);
    const float* Tb = Tg + img * (WW * WW);

    f2 prr[11], trr[11];
    f2 sp = splat(0.f), st = splat(0.f), sq = splat(0.f), sx = splat(0.f);

    // ---- prime: input rows y0..y0+9 into ring slots 0..9 ----
    #pragma unroll
    for (int r = 0; r < 10; ++r) {
        f2 p = ld2(Pb + (y0 + r) * WW + cload);
        f2 t = ld2(Tb + (y0 + r) * WW + cload);
        prr[r] = p; trr[r] = t;
        sp += p; st += t;
        sq = __builtin_elementwise_fma(p, p, sq);
        sq = __builtin_elementwise_fma(t, t, sq);
        sx = __builtin_elementwise_fma(p, t, sx);
    }
    // depth-3 prefetch pipeline: rows y0+10 .. y0+12 (always valid addresses)
    f2 Pn0 = ld2(Pb + (y0 + 10) * WW + cload);
    f2 Tn0 = ld2(Tb + (y0 + 10) * WW + cload);
    f2 Pn1 = ld2(Pb + (y0 + 11) * WW + cload);
    f2 Tn1 = ld2(Tb + (y0 + 11) * WW + cload);
    const int r12 = min(y0 + 12, 511);
    f2 Pn2 = ld2(Pb + r12 * WW + cload);
    f2 Tn2 = ld2(Tb + r12 * WW + cload);

    f2 acc2 = splat(0.f);

    for (int blk = 0; blk < 2; ++blk) {          // 2 x 11 = 22 rows, no guards
        #pragma unroll
        for (int j = 0; j < 11; ++j) {
            const int sn = (10 + j) % 11;        // static ring slot
            const int y  = y0 + 11 * blk + j;    // output row this iter makes
            // consume prefetched row (loaded 3 iterations ago)
            f2 Pc = Pn0, Tc = Tn0;
            // rotate pipeline (straight-line: renamed, no real moves)
            Pn0 = Pn1; Tn0 = Tn1;
            Pn1 = Pn2; Tn1 = Tn2;
            int nr = min(y + 13, 511);
            Pn2 = ld2(Pb + nr * WW + cload);
            Tn2 = ld2(Tb + nr * WW + cload);
            // vertical: add new row (packed fp32)
            prr[sn] = Pc; trr[sn] = Tc;
            sp += Pc; st += Tc;
            sq = __builtin_elementwise_fma(Pc, Pc, sq);
            sq = __builtin_elementwise_fma(Tc, Tc, sq);
            sx = __builtin_elementwise_fma(Pc, Tc, sx);
            // horizontal windows (DPP A-chain + 1 bpermute each) + SSIM
            f2 w0 = hwin(sp, bpa);
            f2 w1 = hwin(st, bpa);
            f2 w2 = hwin(sq, bpa);
            f2 w3 = hwin(sx, bpa);
            if (ok && y < OH) {                  // gate accumulate only
                acc2 += ssim2(w0, w1, w2, w3);
            }
            // vertical: subtract oldest row (ring slot j, packed fp32)
            f2 po = prr[j], to = trr[j];
            sp -= po; st -= to;
            sq = __builtin_elementwise_fma(po, -po, sq);
            sq = __builtin_elementwise_fma(to, -to, sq);
            sx = __builtin_elementwise_fma(po, -to, sx);
        }
    }

    // ---- reduce: wave -> block -> one atomicAdd ----
    float acc = acc2.x + acc2.y;
    #pragma unroll
    for (int off = 32; off > 0; off >>= 1) acc += __shfl_down(acc, off);
    __shared__ float wred[4];
    if (lane == 0) wred[wv] = acc;
    __syncthreads();
    if (tid == 0) {
        float s = wred[0] + wred[1] + wred[2] + wred[3];
        float contrib = -s * INV_N;
        if (blockIdx.x == 0) contrib += 1.0f;
        atomicAdd(outp, contrib);
    }
}

extern "C" void kernel_launch(void* const* d_in, const int* in_sizes, int n_in,
                              void* d_out, int out_size, void* d_ws, size_t ws_size,
                              hipStream_t stream) {
    const float* pred = (const float*)d_in[0];
    const float* targ = (const float*)d_in[1];
    float* out = (float*)d_out;

    hipMemsetAsync(out, 0, sizeof(float), stream);
    ssim_main<<<dim3(920), dim3(256), 0, stream>>>(pred, targ, out);
}